// Round 2
// baseline (20547.350 us; speedup 1.0000x reference)
//
#include <hip/hip_runtime.h>
#include <math.h>

#define BB 32768      // batch
#define SEQL 9        // observed frames
#define EE 16         // embedding dim
#define HH 128        // hidden dim
#define OBS_STEPS 8   // SEQ-1
#define NSTEP 19      // SEQ-1 + n_predict-1

__device__ __forceinline__ float sigm(float x) { return 1.0f / (1.0f + __expf(-x)); }

// load 8 contiguous fp32 (two float4)
__device__ __forceinline__ void load8(const float* __restrict__ p, float* o) {
    float4 a = *reinterpret_cast<const float4*>(p);
    float4 b = *reinterpret_cast<const float4*>(p + 4);
    o[0] = a.x; o[1] = a.y; o[2] = a.z; o[3] = a.w;
    o[4] = b.x; o[5] = b.y; o[6] = b.z; o[7] = b.w;
}

__global__ __launch_bounds__(256) void k_init(float* __restrict__ h0, float* __restrict__ c) {
    int i = blockIdx.x * 256 + threadIdx.x;   // grid covers BB*HH
    h0[i] = 0.0f;
    c[i] = 0.0f;
}

// one thread per (batch, hidden j): computes 4 gates + cell update
__global__ __launch_bounds__(256) void k_cell(
    int s,
    const float* __restrict__ obs,
    const float* __restrict__ W_emb, const float* __restrict__ b_emb,
    const float* __restrict__ W_ih, const float* __restrict__ b_ih,
    const float* __restrict__ W_hh, const float* __restrict__ b_hh,
    const float* __restrict__ h_in, float* __restrict__ h_out,
    float* __restrict__ c,
    const float* __restrict__ pl, const float* __restrict__ pp)
{
    int tid = blockIdx.x * 256 + threadIdx.x;
    int b = tid >> 7;
    int j = tid & 127;

    // ---- input delta ----
    float d0, d1;
    if (s < OBS_STEPS) {
        d0 = obs[(size_t)(s + 1) * BB * 2 + b * 2 + 0] - obs[(size_t)s * BB * 2 + b * 2 + 0];
        d1 = obs[(size_t)(s + 1) * BB * 2 + b * 2 + 1] - obs[(size_t)s * BB * 2 + b * 2 + 1];
    } else {
        d0 = pl[b * 2 + 0] - pp[b * 2 + 0];
        d1 = pl[b * 2 + 1] - pp[b * 2 + 1];
    }

    // ---- embed: relu(W_emb @ delta + b_emb), 16 dims (redundant per thread, tiny) ----
    float x[EE];
#pragma unroll
    for (int e = 0; e < EE; e++) {
        float v = b_emb[e] + d0 * W_emb[2 * e + 0] + d1 * W_emb[2 * e + 1];
        x[e] = v > 0.0f ? v : 0.0f;
    }

    // ---- gates: i,f,g,o rows j, 128+j, 256+j, 384+j ----
    float acc[4];
#pragma unroll
    for (int gi = 0; gi < 4; gi++)
        acc[gi] = b_ih[gi * HH + j] + b_hh[gi * HH + j];

#pragma unroll
    for (int gi = 0; gi < 4; gi++) {
        const float* w = W_ih + (size_t)(gi * HH + j) * EE;
        float wv[8];
        load8(w, wv);
#pragma unroll
        for (int k = 0; k < 8; k++) acc[gi] += x[k] * wv[k];
        load8(w + 8, wv);
#pragma unroll
        for (int k = 0; k < 8; k++) acc[gi] += x[8 + k] * wv[k];
    }

    const float* hb = h_in + (size_t)b * HH;
    const float* w0 = W_hh + (size_t)(0 * HH + j) * HH;
    const float* w1 = W_hh + (size_t)(1 * HH + j) * HH;
    const float* w2 = W_hh + (size_t)(2 * HH + j) * HH;
    const float* w3 = W_hh + (size_t)(3 * HH + j) * HH;
    for (int k = 0; k < HH; k += 8) {
        float hv[8];
#pragma unroll
        for (int t = 0; t < 8; t++) hv[t] = hb[k + t];   // wave-uniform address -> scalar broadcast
        float wv0[8], wv1[8], wv2[8], wv3[8];
        load8(w0 + k, wv0);
        load8(w1 + k, wv1);
        load8(w2 + k, wv2);
        load8(w3 + k, wv3);
#pragma unroll
        for (int t = 0; t < 8; t++) {
            acc[0] += hv[t] * wv0[t];
            acc[1] += hv[t] * wv1[t];
            acc[2] += hv[t] * wv2[t];
            acc[3] += hv[t] * wv3[t];
        }
    }

    float gi_ = sigm(acc[0]);
    float gf_ = sigm(acc[1]);
    float gg_ = tanhf(acc[2]);
    float go_ = sigm(acc[3]);
    float cn = gf_ * c[tid] + gi_ * gg_;
    c[tid] = cn;
    h_out[tid] = go_ * tanhf(cn);
}

// one thread per batch row: readout (2 of 5 outputs) + position update
__global__ __launch_bounds__(256) void k_pos(
    int s,
    const float* __restrict__ obs,
    const float* __restrict__ W_out, const float* __restrict__ b_out,
    const float* __restrict__ h,
    float* __restrict__ pl, float* __restrict__ pp,
    float* __restrict__ out)
{
    int b = blockIdx.x * 256 + threadIdx.x;
    float r0 = b_out[0];
    float r1 = b_out[1];
    const float* hb = h + (size_t)b * HH;
    for (int k = 0; k < HH; k += 8) {
        float w0[8], w1[8];
        load8(W_out + 0 * HH + k, w0);
        load8(W_out + 1 * HH + k, w1);
#pragma unroll
        for (int t = 0; t < 8; t++) {
            float hv = hb[k + t];
            r0 += hv * w0[t];
            r1 += hv * w1[t];
        }
    }
    float base0, base1;
    if (s < OBS_STEPS) {
        base0 = obs[(size_t)(s + 1) * BB * 2 + b * 2 + 0];
        base1 = obs[(size_t)(s + 1) * BB * 2 + b * 2 + 1];
    } else {
        base0 = pl[b * 2 + 0];
        base1 = pl[b * 2 + 1];
    }
    float p0 = base0 + r0;
    float p1 = base1 + r1;
    out[(size_t)s * BB * 2 + b * 2 + 0] = p0;
    out[(size_t)s * BB * 2 + b * 2 + 1] = p1;
    // shift position history (read-before-write within the same thread)
    pp[b * 2 + 0] = pl[b * 2 + 0];
    pp[b * 2 + 1] = pl[b * 2 + 1];
    pl[b * 2 + 0] = p0;
    pl[b * 2 + 1] = p1;
}

extern "C" void kernel_launch(void* const* d_in, const int* in_sizes, int n_in,
                              void* d_out, int out_size, void* d_ws, size_t ws_size,
                              hipStream_t stream)
{
    const float* obs   = (const float*)d_in[0];
    const float* W_emb = (const float*)d_in[1];
    const float* b_emb = (const float*)d_in[2];
    const float* W_ih  = (const float*)d_in[3];
    const float* b_ih  = (const float*)d_in[4];
    const float* W_hh  = (const float*)d_in[5];
    const float* b_hh  = (const float*)d_in[6];
    const float* W_out = (const float*)d_in[7];
    const float* b_out = (const float*)d_in[8];
    float* out = (float*)d_out;

    float* ws = (float*)d_ws;
    float* h0 = ws;
    float* h1 = ws + (size_t)BB * HH;
    float* c  = ws + (size_t)2 * BB * HH;
    float* pl = ws + (size_t)3 * BB * HH;
    float* pp = pl + 2 * BB;
    // ws usage: 3*BB*HH + 4*BB floats ~= 50.9 MB

    hipLaunchKernelGGL(k_init, dim3((BB * HH) / 256), dim3(256), 0, stream, h0, c);

    for (int s = 0; s < NSTEP; s++) {
        const float* hin = (s & 1) ? h1 : h0;
        float* hout      = (s & 1) ? h0 : h1;
        hipLaunchKernelGGL(k_cell, dim3((BB * HH) / 256), dim3(256), 0, stream,
                           s, obs, W_emb, b_emb, W_ih, b_ih, W_hh, b_hh,
                           hin, hout, c, pl, pp);
        hipLaunchKernelGGL(k_pos, dim3(BB / 256), dim3(256), 0, stream,
                           s, obs, W_out, b_out, hout, pl, pp, out);
    }
}

// Round 3
// 1943.256 us; speedup vs baseline: 10.5737x; 10.5737x over previous
//
#include <hip/hip_runtime.h>
#include <math.h>

#define BB 32768
#define EE 16
#define HH 128
#define NG 512          // 4*HH gate columns
#define KC 144          // EE + HH (concatenated input [x|h])
#define KH 72           // per-thread k-slice (half of KC)
#define OBS_STEPS 8
#define NSTEP 19
#define TPB 1024
#define ROWS 64         // batch rows per block
#define CHUNK 8         // rows per gate-exchange chunk
#define NCHUNK 8        // ROWS/CHUNK

__device__ __forceinline__ float sigm(float x) { return 1.0f / (1.0f + __expf(-x)); }

__global__ __launch_bounds__(TPB) void k_lstm(
    const float* __restrict__ obs,
    const float* __restrict__ W_emb, const float* __restrict__ b_emb,
    const float* __restrict__ W_ih,  const float* __restrict__ b_ih,
    const float* __restrict__ W_hh,  const float* __restrict__ b_hh,
    const float* __restrict__ W_out, const float* __restrict__ b_out,
    float* __restrict__ out)
{
    extern __shared__ float smem[];
    float* xh    = smem;                   // [ROWS][KC]   row = [x(16) | h(128)]
    float* gates = xh + ROWS * KC;         // [CHUNK][NG]
    float* plpp  = gates + CHUNK * NG;     // [ROWS][4]    pl0 pl1 pp0 pp1
    float* wemb  = plpp + ROWS * 4;        // [EE][2]
    float* bemb  = wemb + EE * 2;          // [EE]
    float* wout  = bemb + EE;              // [2][HH]
    float* bout2 = wout + 2 * HH;          // [2]

    const int t    = threadIdx.x;
    const int col  = t >> 1;       // gate column 0..511 (i,f,g,o blocks of 128)
    const int half = t & 1;        // k-slice: 0 -> [0,72), 1 -> [72,144)
    const int row0 = blockIdx.x * ROWS;

    // ---- per-thread weight slice in registers (cat space [W_ih | W_hh]) ----
    float w[KH];
    if (half == 0) {
#pragma unroll
        for (int k = 0; k < EE; k++)      w[k]      = W_ih[col * EE + k];
#pragma unroll
        for (int k = 0; k < KH - EE; k++) w[EE + k] = W_hh[col * HH + k];
    } else {
#pragma unroll
        for (int k = 0; k < KH; k++)      w[k]      = W_hh[col * HH + (KH - EE) + k];
    }
    const float bias = b_ih[col] + b_hh[col];

    // ---- small weights into LDS ----
    if (t < EE * 2) wemb[t]  = W_emb[t];
    if (t < EE)     bemb[t]  = b_emb[t];
    if (t < 2 * HH) wout[t]  = W_out[t];   // rows 0,1 of W_out (only ones needed)
    if (t < 2)      bout2[t] = b_out[t];

    // ---- zero h region ----
    for (int i = t; i < ROWS * HH; i += TPB) {
        int r = i >> 7, j = i & (HH - 1);
        xh[r * KC + EE + j] = 0.0f;
    }

    float c[NCHUNK];
#pragma unroll
    for (int q = 0; q < NCHUNK; q++) c[q] = 0.0f;

    __syncthreads();

#pragma unroll 1
    for (int s = 0; s < NSTEP; s++) {
        // ================= embed: x = relu(W_emb @ delta + b_emb) =================
        {
            int row = t >> 4;          // 16 e-slots per row, 1 item/thread
            int e   = t & 15;
            float d0, d1;
            if (s < OBS_STEPS) {
                int g = (row0 + row) * 2;
                d0 = obs[(size_t)(s + 1) * BB * 2 + g]     - obs[(size_t)s * BB * 2 + g];
                d1 = obs[(size_t)(s + 1) * BB * 2 + g + 1] - obs[(size_t)s * BB * 2 + g + 1];
            } else {
                d0 = plpp[row * 4 + 0] - plpp[row * 4 + 2];
                d1 = plpp[row * 4 + 1] - plpp[row * 4 + 3];
            }
            float v = bemb[e] + d0 * wemb[e * 2] + d1 * wemb[e * 2 + 1];
            xh[row * KC + e] = v > 0.0f ? v : 0.0f;
        }
        __syncthreads();

        // ================= gates + cell update, 8-row chunks =================
#pragma unroll 1
        for (int ch = 0; ch < NCHUNK; ch++) {
#pragma unroll 1
            for (int rp = 0; rp < CHUNK / 2; rp++) {
                int r0 = ch * CHUNK + rp * 2;
                const float* p0 = xh + r0 * KC + half * KH;
                const float* p1 = p0 + KC;
                float a0 = 0.0f, a1 = 0.0f;
#pragma unroll
                for (int kk = 0; kk < KH / 4; kk++) {
                    float4 u0 = *reinterpret_cast<const float4*>(p0 + kk * 4);
                    float4 u1 = *reinterpret_cast<const float4*>(p1 + kk * 4);
                    a0 += w[kk * 4 + 0] * u0.x; a0 += w[kk * 4 + 1] * u0.y;
                    a0 += w[kk * 4 + 2] * u0.z; a0 += w[kk * 4 + 3] * u0.w;
                    a1 += w[kk * 4 + 0] * u1.x; a1 += w[kk * 4 + 1] * u1.y;
                    a1 += w[kk * 4 + 2] * u1.z; a1 += w[kk * 4 + 3] * u1.w;
                }
                a0 += __shfl_xor(a0, 1);      // combine k-halves (lane pair)
                a1 += __shfl_xor(a1, 1);
                if (half == 0) {
                    gates[(rp * 2)     * NG + col] = a0 + bias;
                    gates[(rp * 2 + 1) * NG + col] = a1 + bias;
                }
            }
            __syncthreads();
            // elementwise LSTM update: 8 rows x 128 = 1024 items, 1/thread
            {
                int rr = t >> 7, j = t & (HH - 1);
                float gi = gates[rr * NG + j];
                float gf = gates[rr * NG + HH + j];
                float gg = gates[rr * NG + 2 * HH + j];
                float go = gates[rr * NG + 3 * HH + j];
                float cn = sigm(gf) * c[ch] + sigm(gi) * tanhf(gg);
                c[ch] = cn;
                xh[(ch * CHUNK + rr) * KC + EE + j] = sigm(go) * tanhf(cn);
            }
            __syncthreads();
        }

        // ================= readout + position update =================
        {
            int rc = t >> 3, ks = t & 7;     // rc 0..127 = (row, out-col)
            int row = rc >> 1, oc = rc & 1;
            const float* hp = xh + row * KC + EE + ks * 16;
            const float* wp = wout + oc * HH + ks * 16;
            float p = 0.0f;
#pragma unroll
            for (int kk = 0; kk < 4; kk++) {
                float4 hv = *reinterpret_cast<const float4*>(hp + kk * 4);
                float4 wv = *reinterpret_cast<const float4*>(wp + kk * 4);
                p += wv.x * hv.x + wv.y * hv.y + wv.z * hv.z + wv.w * hv.w;
            }
            p += __shfl_xor(p, 1);
            p += __shfl_xor(p, 2);
            p += __shfl_xor(p, 4);
            if (ks == 0) {
                float base;
                if (s < OBS_STEPS) base = obs[(size_t)(s + 1) * BB * 2 + (row0 + row) * 2 + oc];
                else               base = plpp[row * 4 + oc];
                float pos = base + p + bout2[oc];
                out[((size_t)s * BB + row0 + row) * 2 + oc] = pos;
                plpp[row * 4 + 2 + oc] = plpp[row * 4 + oc];   // pp <- pl
                plpp[row * 4 + oc]     = pos;                   // pl <- pos
            }
        }
        __syncthreads();
    }
}

extern "C" void kernel_launch(void* const* d_in, const int* in_sizes, int n_in,
                              void* d_out, int out_size, void* d_ws, size_t ws_size,
                              hipStream_t stream)
{
    const float* obs   = (const float*)d_in[0];
    const float* W_emb = (const float*)d_in[1];
    const float* b_emb = (const float*)d_in[2];
    const float* W_ih  = (const float*)d_in[3];
    const float* b_ih  = (const float*)d_in[4];
    const float* W_hh  = (const float*)d_in[5];
    const float* b_hh  = (const float*)d_in[6];
    const float* W_out = (const float*)d_in[7];
    const float* b_out = (const float*)d_in[8];
    float* out = (float*)d_out;

    const size_t lds_bytes =
        (ROWS * KC + CHUNK * NG + ROWS * 4 + EE * 2 + EE + 2 * HH + 2) * sizeof(float);

    hipLaunchKernelGGL(k_lstm, dim3(BB / ROWS), dim3(TPB), lds_bytes, stream,
                       obs, W_emb, b_emb, W_ih, b_ih, W_hh, b_hh, W_out, b_out, out);
}

// Round 4
// 1332.007 us; speedup vs baseline: 15.4259x; 1.4589x over previous
//
#include <hip/hip_runtime.h>
#include <math.h>

#define BB 32768
#define EE 16
#define HH 128
#define KC 144        // EE + HH
#define NG 512        // 4*HH
#define OBS 8
#define NSTEP 19
#define TPB 256
#define ROWS 32       // rows per block
#define RPW 8         // rows per wave (4 waves/block)
#define NQ 36         // KC/4 k-quads

__device__ __forceinline__ float sigm(float x) { return 1.0f / (1.0f + __expf(-x)); }

// Pack Wt[k][j*4+g] = (k<EE ? W_ih : W_hh)[col=g*128+j][k(-EE)]; bt[j*4+g] = b_ih+b_hh.
__global__ __launch_bounds__(256) void k_prep(
    const float* __restrict__ W_ih, const float* __restrict__ b_ih,
    const float* __restrict__ W_hh, const float* __restrict__ b_hh,
    float* __restrict__ Wt, float* __restrict__ bt)
{
    int idx = blockIdx.x * 256 + threadIdx.x;
    if (idx < KC * NG) {
        int k = idx >> 9, jg = idx & 511;
        int j = jg >> 2, g = jg & 3, col = g * HH + j;
        Wt[idx] = (k < EE) ? W_ih[col * EE + k] : W_hh[col * HH + (k - EE)];
    }
    if (idx < NG) {
        int j = idx >> 2, g = idx & 3, col = g * HH + j;
        bt[idx] = b_ih[col] + b_hh[col];
    }
}

__global__ __launch_bounds__(TPB, 2) void k_lstm(
    const float* __restrict__ obs,
    const float* __restrict__ W_emb, const float* __restrict__ b_emb,
    const float* __restrict__ Wt,    const float* __restrict__ bt,
    const float* __restrict__ W_out, const float* __restrict__ b_out,
    float* __restrict__ out)
{
    __shared__ float xh[ROWS * KC];      // per-wave-private row slices
    __shared__ float plpp[ROWS * 4];     // pl0 pl1 pp0 pp1 per row

    const int t  = threadIdx.x;
    const int tc = t & 63;               // lane
    const int tr = t >> 6;               // wave id 0..3
    const int rowL0 = tr * RPW;          // first local row of this wave
    const int row0  = blockIdx.x * ROWS + rowL0;

    // per-thread column bias (cols jg = tc*8 .. tc*8+7)
    float bias8[8];
    {
        float4 b0 = *reinterpret_cast<const float4*>(&bt[tc * 8]);
        float4 b1 = *reinterpret_cast<const float4*>(&bt[tc * 8 + 4]);
        bias8[0]=b0.x; bias8[1]=b0.y; bias8[2]=b0.z; bias8[3]=b0.w;
        bias8[4]=b1.x; bias8[5]=b1.y; bias8[6]=b1.z; bias8[7]=b1.w;
    }
    // readout weights for this lane's j-pair
    float wo00 = W_out[0 * HH + tc * 2], wo01 = W_out[0 * HH + tc * 2 + 1];
    float wo10 = W_out[1 * HH + tc * 2], wo11 = W_out[1 * HH + tc * 2 + 1];
    const float bo0 = b_out[0], bo1 = b_out[1];
    // embed weights for this lane's e-slot (e = tc&15)
    const int e_ = tc & 15;
    const float we0 = W_emb[2 * e_], we1 = W_emb[2 * e_ + 1], be = b_emb[e_];

    float c[RPW][2];
#pragma unroll
    for (int r = 0; r < RPW; r++) { c[r][0] = 0.0f; c[r][1] = 0.0f; }

    // zero own h region (wave-private; no barrier needed anywhere)
#pragma unroll
    for (int r = 0; r < RPW; r++) {
        xh[(rowL0 + r) * KC + EE + tc * 2]     = 0.0f;
        xh[(rowL0 + r) * KC + EE + tc * 2 + 1] = 0.0f;
    }

#pragma unroll 1
    for (int s = 0; s < NSTEP; s++) {
        // ---------- embed: relu(W_emb@delta + b_emb), rows wave-private ----------
#pragma unroll
        for (int pass = 0; pass < 2; pass++) {
            int rl = (tc >> 4) + pass * 4;          // local row 0..7
            int grow = row0 + rl;
            float d0, d1;
            if (s < OBS) {
                d0 = obs[(size_t)(s + 1) * BB * 2 + grow * 2]     - obs[(size_t)s * BB * 2 + grow * 2];
                d1 = obs[(size_t)(s + 1) * BB * 2 + grow * 2 + 1] - obs[(size_t)s * BB * 2 + grow * 2 + 1];
            } else {
                const float* p4 = &plpp[(rowL0 + rl) * 4];
                d0 = p4[0] - p4[2];
                d1 = p4[1] - p4[3];
            }
            float v = be + d0 * we0 + d1 * we1;
            xh[(rowL0 + rl) * KC + e_] = v > 0.0f ? v : 0.0f;
        }

        // ---------- gates: acc[r][cc], cc = jj*4+g ----------
        float acc[RPW][8];
#pragma unroll
        for (int r = 0; r < RPW; r++)
#pragma unroll
            for (int cc = 0; cc < 8; cc++) acc[r][cc] = bias8[cc];

#pragma unroll 1
        for (int kq = 0; kq < NQ; kq++) {
            float4 xv[RPW];
#pragma unroll
            for (int r = 0; r < RPW; r++)
                xv[r] = *reinterpret_cast<const float4*>(&xh[(rowL0 + r) * KC + kq * 4]);
#pragma unroll
            for (int kk = 0; kk < 4; kk++) {
                const float* wrow = &Wt[(size_t)(kq * 4 + kk) * NG + tc * 8];
                float4 wa = *reinterpret_cast<const float4*>(wrow);
                float4 wb = *reinterpret_cast<const float4*>(wrow + 4);
#pragma unroll
                for (int r = 0; r < RPW; r++) {
                    float xk = (kk == 0) ? xv[r].x : (kk == 1) ? xv[r].y : (kk == 2) ? xv[r].z : xv[r].w;
                    acc[r][0] += xk * wa.x; acc[r][1] += xk * wa.y;
                    acc[r][2] += xk * wa.z; acc[r][3] += xk * wa.w;
                    acc[r][4] += xk * wb.x; acc[r][5] += xk * wb.y;
                    acc[r][6] += xk * wb.z; acc[r][7] += xk * wb.w;
                }
            }
        }

        // ---------- cell update + h writeback + readout partials ----------
        float red[RPW][2];
#pragma unroll
        for (int r = 0; r < RPW; r++) {
            float h0, h1;
            {
                float gi = sigm(acc[r][0]), gf = sigm(acc[r][1]);
                float gg = tanhf(acc[r][2]), go = sigm(acc[r][3]);
                float cn = gf * c[r][0] + gi * gg;
                c[r][0] = cn;
                h0 = go * tanhf(cn);
            }
            {
                float gi = sigm(acc[r][4]), gf = sigm(acc[r][5]);
                float gg = tanhf(acc[r][6]), go = sigm(acc[r][7]);
                float cn = gf * c[r][1] + gi * gg;
                c[r][1] = cn;
                h1 = go * tanhf(cn);
            }
            *reinterpret_cast<float2*>(&xh[(rowL0 + r) * KC + EE + tc * 2]) = make_float2(h0, h1);
            red[r][0] = h0 * wo00 + h1 * wo01;
            red[r][1] = h0 * wo10 + h1 * wo11;
        }

        // butterfly reduce over the 64 lanes (rows are wave-private)
#pragma unroll
        for (int mask = 1; mask < 64; mask <<= 1) {
#pragma unroll
            for (int r = 0; r < RPW; r++) {
                red[r][0] += __shfl_xor(red[r][0], mask, 64);
                red[r][1] += __shfl_xor(red[r][1], mask, 64);
            }
        }

        if (tc == 0) {
#pragma unroll
            for (int r = 0; r < RPW; r++) {
                int grow = row0 + r;
#pragma unroll
                for (int oc = 0; oc < 2; oc++) {
                    float base = (s < OBS)
                        ? obs[(size_t)(s + 1) * BB * 2 + grow * 2 + oc]
                        : plpp[(rowL0 + r) * 4 + oc];
                    float pos = base + red[r][oc] + (oc ? bo1 : bo0);
                    out[((size_t)s * BB + grow) * 2 + oc] = pos;
                    plpp[(rowL0 + r) * 4 + 2 + oc] = plpp[(rowL0 + r) * 4 + oc];  // pp <- pl
                    plpp[(rowL0 + r) * 4 + oc]     = pos;                          // pl <- pos
                }
            }
        }
        // no __syncthreads: all state (xh rows, plpp rows, c) is wave-private
    }
}

extern "C" void kernel_launch(void* const* d_in, const int* in_sizes, int n_in,
                              void* d_out, int out_size, void* d_ws, size_t ws_size,
                              hipStream_t stream)
{
    const float* obs   = (const float*)d_in[0];
    const float* W_emb = (const float*)d_in[1];
    const float* b_emb = (const float*)d_in[2];
    const float* W_ih  = (const float*)d_in[3];
    const float* b_ih  = (const float*)d_in[4];
    const float* W_hh  = (const float*)d_in[5];
    const float* b_hh  = (const float*)d_in[6];
    const float* W_out = (const float*)d_in[7];
    const float* b_out = (const float*)d_in[8];
    float* out = (float*)d_out;

    float* Wt = (float*)d_ws;                 // [144][512]
    float* bt = Wt + KC * NG;                 // [512]

    hipLaunchKernelGGL(k_prep, dim3((KC * NG + 255) / 256), dim3(256), 0, stream,
                       W_ih, b_ih, W_hh, b_hh, Wt, bt);

    hipLaunchKernelGGL(k_lstm, dim3(BB / ROWS), dim3(TPB), 0, stream,
                       obs, W_emb, b_emb, Wt, bt, W_out, b_out, out);
}